// Round 9
// baseline (346.067 us; speedup 1.0000x reference)
//
#include <hip/hip_runtime.h>
#include <stdint.h>

// ---------------------------------------------------------------------------
// Fused: Q=x@Wq^T+bq; K=y@Wk^T+bk; V=y@Wv^T+bv; ctx=softmax(QK^T/sqrt(384))@V
//        out = (x + ctx/||ctx||_row) @ Wo^T + bo        (N=M=8192, D=384)
// softmax: no max-subtraction needed (logit sigma ~0.33); denominator cancels
// under F.normalize. Scale*log2e folded into Q projection -> P = exp2(S).
// v9 = r4-green base (gemm_nt x4, f32 ctx, f32 flash epilogue, f32 combine —
// all verbatim from the passing r4) + ONE change: flash uses the counted-
// vmcnt pipeline (K tri-buf 2-deep via dh0, V dbuf 1-deep via dh1,
// vmcnt(6)+lgkmcnt(0)+barrier A, pure-sync barrier B before V issue; no
// vmcnt(0) drain except t=63). Forensics: merged-GEMM kernels caused the
// r5-r7 aborts (r7 = r4-flash + merged -> abort; r8 = no merged -> ran);
// bf16-ctx caused r8's NaN (mechanism unfound) -> dropped permanently.
// ws layout: Qb bf16[8192,384]@0; Kb@6291456; Vt bf16[384,8192]@12582912;
//            Xn bf16[8192,384]@18874368; ctx f32[4][8192,384]@25165824
// ---------------------------------------------------------------------------

typedef __attribute__((ext_vector_type(8))) short bf16x8;
typedef __attribute__((ext_vector_type(4))) float f32x4;
typedef __attribute__((ext_vector_type(16))) float f32x16;

#define DEV static __device__ __forceinline__

DEV short f2bf(float f) {
  uint32_t u = __builtin_bit_cast(uint32_t, f);
  u += 0x7fffu + ((u >> 16) & 1u);
  return (short)(u >> 16);
}
DEV uint32_t pack2(float a, float b) {
  return (uint32_t)(uint16_t)f2bf(a) | ((uint32_t)(uint16_t)f2bf(b) << 16);
}
DEV unsigned cvt_pk(float lo, float hi) {
  unsigned r;
  asm("v_cvt_pk_bf16_f32 %0, %1, %2" : "=v"(r) : "v"(lo), "v"(hi));
  return r;
}
DEV void pl32swap(unsigned& a, unsigned& b) {
  asm volatile("v_permlane32_swap_b32 %0, %1" : "+v"(a), "+v"(b));
}
DEV void gload16(const void* g, void* l) {
  __builtin_amdgcn_global_load_lds(
      (const __attribute__((address_space(1))) unsigned*)g,
      (__attribute__((address_space(3))) unsigned*)l, 16, 0, 0);
}

// ---------------------------------------------------------------------------
// Generic GEMM-NT: C[m,n] = (sum_k A[m,k]*B[n,k] + bias) * scale   (r4-proven)
// ---------------------------------------------------------------------------
template <int BIAS_ON_N, int OUT_F32, int A_F32>
__global__ __launch_bounds__(256) void gemm_nt(
    const void* __restrict__ Aptr, const float* __restrict__ B,
    const float* __restrict__ bias, void* __restrict__ Cptr,
    int M, int N, int K, float scale) {
  __shared__ char As[128 * 128];
  __shared__ char Bs[128 * 128];
  const int tid = threadIdx.x;
  const int l = tid & 63, w = tid >> 6;
  const int lq = l & 15, lk = l >> 4;
  const int m0 = blockIdx.x * 128, n0 = blockIdx.y * 128;
  const int wr = (w >> 1) * 64, wc = (w & 1) * 64;
  f32x4 acc[4][4] = {};

  for (int k0 = 0; k0 < K; k0 += 64) {
    if (A_F32) {
      const float* A = (const float*)Aptr;
#pragma unroll
      for (int i = 0; i < 8; i++) {
        int c = tid + i * 256;
        int row = c >> 4, col = (c & 15) * 4;
        f32x4 v = *(const f32x4*)(A + (size_t)(m0 + row) * K + k0 + col);
        uint32_t lo = pack2(v.x, v.y), hi = pack2(v.z, v.w);
        int off = (row * 128 + col * 2) ^ ((row & 7) << 4);
        *(uint32_t*)(As + off) = lo;
        *(uint32_t*)(As + off + 4) = hi;
      }
    } else {
      const short* A = (const short*)Aptr;
#pragma unroll
      for (int i = 0; i < 4; i++) {
        int c = tid + i * 256;
        int row = c >> 3, col = (c & 7) * 8;
        uint4 v = *(const uint4*)(A + (size_t)(m0 + row) * K + k0 + col);
        int off = (row * 128 + col * 2) ^ ((row & 7) << 4);
        *(uint4*)(As + off) = v;
      }
    }
#pragma unroll
    for (int i = 0; i < 8; i++) {
      int c = tid + i * 256;
      int row = c >> 4, col = (c & 15) * 4;
      f32x4 v = *(const f32x4*)(B + (size_t)(n0 + row) * K + k0 + col);
      uint32_t lo = pack2(v.x, v.y), hi = pack2(v.z, v.w);
      int off = (row * 128 + col * 2) ^ ((row & 7) << 4);
      *(uint32_t*)(Bs + off) = lo;
      *(uint32_t*)(Bs + off + 4) = hi;
    }
    __syncthreads();
#pragma unroll
    for (int ks = 0; ks < 2; ks++) {
      bf16x8 af[4], bfr[4];
#pragma unroll
      for (int m = 0; m < 4; m++) {
        int row = wr + m * 16 + lq;
        af[m] = *(const bf16x8*)(As + ((row * 128 + ks * 64 + lk * 16) ^ ((row & 7) << 4)));
      }
#pragma unroll
      for (int n = 0; n < 4; n++) {
        int row = wc + n * 16 + lq;
        bfr[n] = *(const bf16x8*)(Bs + ((row * 128 + ks * 64 + lk * 16) ^ ((row & 7) << 4)));
      }
#pragma unroll
      for (int m = 0; m < 4; m++)
#pragma unroll
        for (int n = 0; n < 4; n++)
          acc[m][n] = __builtin_amdgcn_mfma_f32_16x16x32_bf16(af[m], bfr[n], acc[m][n], 0, 0, 0);
    }
    __syncthreads();
  }
#pragma unroll
  for (int m = 0; m < 4; m++) {
    int mg = m0 + wr + m * 16 + lk * 4;
#pragma unroll
    for (int n = 0; n < 4; n++) {
      int ng = n0 + wc + n * 16 + lq;
#pragma unroll
      for (int r = 0; r < 4; r++) {
        float v = (acc[m][n][r] + (BIAS_ON_N ? bias[ng] : bias[mg + r])) * scale;
        if (OUT_F32)
          ((float*)Cptr)[(size_t)(mg + r) * N + ng] = v;
        else
          ((short*)Cptr)[(size_t)(mg + r) * N + ng] = f2bf(v);
      }
    }
  }
}

// ---------------------------------------------------------------------------
// Flash numerator v9. Grid 256 = 64 q-tiles x 4 splits (split=bid&3 -> XCD-
// pinned). Block 512 = 8 waves: (qh=w&3, dh=w>>2), 32q x 192d each.
// Duty QK on dh==t&1; P via LDS dbuf; PV(t-1) all waves. Counted-vmcnt
// pipeline: dh0 stages K(t+2) (tri-buf), dh1 stages V(t+1) (dbuf, issued
// after barrier B so PV(t-1) readers are done). Producer waits its OWN
// vmcnt(6) then barrier A publishes; vmcnt(0) only at t=63.
// LDS = 3*24K (K) + 2*24K (V) + 16K (P) = 139264 B (r4-proven size).
// Epilogue/combine identical to r4 (f32 ctx).
// ---------------------------------------------------------------------------
#define ITERS 64

__global__ __launch_bounds__(512)
__attribute__((amdgpu_waves_per_eu(2, 2))) void flash_attn(
    const short* __restrict__ Qb, const short* __restrict__ Kb,
    const short* __restrict__ Vt, float* __restrict__ ctx_part) {
  __shared__ char Ks[3][24576];    // K(t) in Ks[t%3], [32 kv][768B] swz (row&7)<<4
  __shared__ char Vs[2][24576];    // V(t) in Vs[t&1], [384 d][64B] swz ((row>>1)&3)<<4
  __shared__ char Ps[2][4][2048];  // per qh: [32 q][64B], dbuf
  const int tid = threadIdx.x, l = tid & 63, w = tid >> 6;
  const int l31 = l & 31, h = l >> 5;
  const int qh = w & 3, dh = w >> 2;
  const int sp = blockIdx.x & 3, qt = blockIdx.x >> 2;
  const int q0 = qt * 128 + qh * 32;
  const int kvbase = sp * 2048;
  const int pswz = ((l31 >> 2) & 7) << 4;
  const int poff = (l31 * 32 + h * 16) ^ pswz;  // P byte offset (write==read)

  // staging offsets: waves 0-3 stage K, waves 4-7 stage V (pre-swizzled gsrc)
  int off6[6];
  const int cb = (w & 3) * 6144;  // LDS chunk base within tile buffer
  if (dh == 0) {
#pragma unroll
    for (int i = 0; i < 6; i++) {
      int d = cb + i * 1024 + l * 16;
      int krow = d / 768, kc = d - krow * 768;
      off6[i] = krow * 768 + (kc ^ ((krow & 7) << 4));
    }
  } else {
#pragma unroll
    for (int i = 0; i < 6; i++) {
      int d = cb + i * 1024 + l * 16;
      int vrow = d >> 6, vc = d & 63;
      off6[i] = vrow * 16384 + (vc ^ (((vrow >> 1) & 3) << 4));
    }
  }

  // Q B-frags resident: col q = q0+l31, k = s*16 + h*8 + j  (96 VGPR)
  bf16x8 qf[24];
  {
    const short* qrow = Qb + (size_t)(q0 + l31) * 384 + h * 8;
#pragma unroll
    for (int s = 0; s < 24; s++) qf[s] = *(const bf16x8*)(qrow + s * 16);
  }

  // prologue: dh0 stages K(0)->Ks[0], K(1)->Ks[1]; dh1 stages V(0)->Vs[0]
  if (dh == 0) {
    const char* kb0 = (const char*)Kb + (size_t)kvbase * 768;
#pragma unroll
    for (int i = 0; i < 6; i++) gload16(kb0 + off6[i], Ks[0] + cb + i * 1024);
    const char* kb1 = (const char*)Kb + (size_t)(kvbase + 32) * 768;
#pragma unroll
    for (int i = 0; i < 6; i++) gload16(kb1 + off6[i], Ks[1] + cb + i * 1024);
  } else {
    const char* vb0 = (const char*)Vt + (size_t)kvbase * 2;
#pragma unroll
    for (int i = 0; i < 6; i++) gload16(vb0 + off6[i], Vs[0] + cb + i * 1024);
  }

  f32x16 acc[6] = {};

#pragma unroll 1
  for (int t = 0; t < ITERS; t++) {
    // ---- barrier A: producer waits own counter, barrier publishes ----
    // dh0 newest-6 = K(t+1) -> vmcnt(6) proves K(t) landed.
    // dh1 newest-6 = V(t)   -> vmcnt(6) proves V(t-1) landed.
    if (t == ITERS - 1)
      asm volatile("s_waitcnt vmcnt(0)" ::: "memory");
    else
      asm volatile("s_waitcnt vmcnt(6)" ::: "memory");
    asm volatile("s_waitcnt lgkmcnt(0)" ::: "memory");
    __builtin_amdgcn_s_barrier();

    // ---- dh0: issue K(t+2) into Ks[(t+2)%3] (readers done at t-1) ----
    if (dh == 0 && t + 2 < ITERS) {
      const char* kb = (const char*)Kb + (size_t)(kvbase + (t + 2) * 32) * 768;
      char* dst = Ks[(t + 2) % 3] + cb;
#pragma unroll
      for (int i = 0; i < 6; i++) gload16(kb + off6[i], dst + i * 1024);
    }

    // ---- QK(t) duty: S^T = K Q^T -> P -> LDS ----
    if (dh == (t & 1)) {
      f32x16 S = {};
      const char* kcb = Ks[t % 3] + l31 * 768;
      const int swzk = (l31 & 7) << 4;
      __builtin_amdgcn_s_setprio(1);
#pragma unroll
      for (int s = 0; s < 24; s++) {
        bf16x8 k0 = *(const bf16x8*)(kcb + ((s * 32 + h * 16) ^ swzk));
        S = __builtin_amdgcn_mfma_f32_32x32x16_bf16(k0, qf[s], S, 0, 0, 0);
      }
      __builtin_amdgcn_s_setprio(0);
      unsigned a0 = cvt_pk(__builtin_amdgcn_exp2f(S[0]), __builtin_amdgcn_exp2f(S[1]));
      unsigned a1 = cvt_pk(__builtin_amdgcn_exp2f(S[2]), __builtin_amdgcn_exp2f(S[3]));
      unsigned a2 = cvt_pk(__builtin_amdgcn_exp2f(S[4]), __builtin_amdgcn_exp2f(S[5]));
      unsigned a3 = cvt_pk(__builtin_amdgcn_exp2f(S[6]), __builtin_amdgcn_exp2f(S[7]));
      pl32swap(a0, a2); pl32swap(a1, a3);
      uint4 pw0 = {a0, a1, a2, a3};
      unsigned b0 = cvt_pk(__builtin_amdgcn_exp2f(S[8]), __builtin_amdgcn_exp2f(S[9]));
      unsigned b1 = cvt_pk(__builtin_amdgcn_exp2f(S[10]), __builtin_amdgcn_exp2f(S[11]));
      unsigned b2 = cvt_pk(__builtin_amdgcn_exp2f(S[12]), __builtin_amdgcn_exp2f(S[13]));
      unsigned b3 = cvt_pk(__builtin_amdgcn_exp2f(S[14]), __builtin_amdgcn_exp2f(S[15]));
      pl32swap(b0, b2); pl32swap(b1, b3);
      uint4 pw1 = {b0, b1, b2, b3};
      char* pwb = Ps[t & 1][qh];
      *(uint4*)(pwb + poff) = pw0;
      *(uint4*)(pwb + 1024 + poff) = pw1;
    }

    // ---- PV(t-1): all waves, own (qh,dh) partition ----
    if (t > 0) {
      const char* pb = Ps[(t - 1) & 1][qh];
      bf16x8 pf0 = *(const bf16x8*)(pb + poff);
      bf16x8 pf1 = *(const bf16x8*)(pb + 1024 + poff);
      const char* vb = Vs[(t - 1) & 1];
      __builtin_amdgcn_s_setprio(1);
#pragma unroll
      for (int nf = 0; nf < 6; nf++) {
        int vr = dh * 192 + nf * 32 + l31;
        int swz = ((vr >> 1) & 3) << 4;
        const char* vrow = vb + vr * 64;
        bf16x8 v0 = *(const bf16x8*)(vrow + ((h * 16) ^ swz));
        bf16x8 v1 = *(const bf16x8*)(vrow + ((32 + h * 16) ^ swz));
        acc[nf] = __builtin_amdgcn_mfma_f32_32x32x16_bf16(v0, pf0, acc[nf], 0, 0, 0);
        acc[nf] = __builtin_amdgcn_mfma_f32_32x32x16_bf16(v1, pf1, acc[nf], 0, 0, 0);
      }
      __builtin_amdgcn_s_setprio(0);
    }

    // ---- barrier B: V(t-1) readers done -> dh1 may overwrite Vs[(t+1)&1] --
    asm volatile("s_waitcnt lgkmcnt(0)" ::: "memory");
    __builtin_amdgcn_s_barrier();
    if (dh == 1 && t + 1 < ITERS) {
      const char* vb = (const char*)Vt + (size_t)(kvbase + (t + 1) * 32) * 2;
      char* dst = Vs[(t + 1) & 1] + cb;
#pragma unroll
      for (int i = 0; i < 6; i++) gload16(vb + off6[i], dst + i * 1024);
    }
  }

  // ---- tail: publish V(63)/P(63), then PV(63) ----
  asm volatile("s_waitcnt vmcnt(0)" ::: "memory");
  asm volatile("s_waitcnt lgkmcnt(0)" ::: "memory");
  __builtin_amdgcn_s_barrier();
  {
    const char* pb = Ps[(ITERS - 1) & 1][qh];
    bf16x8 pf0 = *(const bf16x8*)(pb + poff);
    bf16x8 pf1 = *(const bf16x8*)(pb + 1024 + poff);
    const char* vb = Vs[(ITERS - 1) & 1];
#pragma unroll
    for (int nf = 0; nf < 6; nf++) {
      int vr = dh * 192 + nf * 32 + l31;
      int swz = ((vr >> 1) & 3) << 4;
      const char* vrow = vb + vr * 64;
      bf16x8 v0 = *(const bf16x8*)(vrow + ((h * 16) ^ swz));
      bf16x8 v1 = *(const bf16x8*)(vrow + ((32 + h * 16) ^ swz));
      acc[nf] = __builtin_amdgcn_mfma_f32_32x32x16_bf16(v0, pf0, acc[nf], 0, 0, 0);
      acc[nf] = __builtin_amdgcn_mfma_f32_32x32x16_bf16(v1, pf1, acc[nf], 0, 0, 0);
    }
  }

  // ---- epilogue: f32 ctx_part[sp][q][d]; lane owns one q row (r4 verbatim) -
  float* outp = ctx_part + (size_t)sp * 8192 * 384 + (size_t)(q0 + l31) * 384;
#pragma unroll
  for (int nf = 0; nf < 6; nf++) {
#pragma unroll
    for (int qd = 0; qd < 4; qd++) {
      f32x4 v = {acc[nf][qd * 4 + 0], acc[nf][qd * 4 + 1],
                 acc[nf][qd * 4 + 2], acc[nf][qd * 4 + 3]};
      *(f32x4*)(outp + dh * 192 + nf * 32 + qd * 8 + h * 4) = v;
    }
  }
}

// ---------------------------------------------------------------------------
// Combine (r4 verbatim): ctx = sum splits; Xn = bf16(x + ctx/||ctx||).
// ---------------------------------------------------------------------------
__global__ __launch_bounds__(256) void combine_norm(
    const float* __restrict__ ctx_part, const float* __restrict__ x,
    short* __restrict__ Xn) {
  const int l = threadIdx.x & 63, w = threadIdx.x >> 6;
  const int q = blockIdx.x * 4 + w;
  const size_t SLAB = (size_t)8192 * 384;
  float v[6];
  float ss = 0.f;
#pragma unroll
  for (int i = 0; i < 6; i++) {
    size_t off = (size_t)q * 384 + i * 64 + l;
    float s = ctx_part[off] + ctx_part[off + SLAB] + ctx_part[off + 2 * SLAB] +
              ctx_part[off + 3 * SLAB];
    v[i] = s;
    ss += s * s;
  }
#pragma unroll
  for (int m = 1; m <= 32; m <<= 1) ss += __shfl_xor(ss, m);
  float inv = 1.0f / fmaxf(sqrtf(ss), 1e-12f);
#pragma unroll
  for (int i = 0; i < 6; i++) {
    size_t off = (size_t)q * 384 + i * 64 + l;
    Xn[off] = f2bf(x[off] + v[i] * inv);
  }
}

// ---------------------------------------------------------------------------
extern "C" void kernel_launch(void* const* d_in, const int* in_sizes, int n_in,
                              void* d_out, int out_size, void* d_ws, size_t ws_size,
                              hipStream_t stream) {
  (void)in_sizes; (void)n_in; (void)out_size; (void)ws_size;
  const float* x  = (const float*)d_in[0];
  const float* y  = (const float*)d_in[1];
  const float* Wq = (const float*)d_in[2];
  const float* bq = (const float*)d_in[3];
  const float* Wk = (const float*)d_in[4];
  const float* bk = (const float*)d_in[5];
  const float* Wv = (const float*)d_in[6];
  const float* bv = (const float*)d_in[7];
  const float* Wo = (const float*)d_in[8];
  const float* bo = (const float*)d_in[9];

  char* ws = (char*)d_ws;
  short* Qb = (short*)(ws);
  short* Kb = (short*)(ws + 6291456);
  short* Vt = (short*)(ws + 12582912);
  short* Xn = (short*)(ws + 18874368);
  float* ctx = (float*)(ws + 25165824);  // f32 [4][8192][384]

  const float SC = 0.07362233f;  // (1/sqrt(384)) * log2(e), folded into Q
  dim3 blk(256);
  gemm_nt<1, 0, 1><<<dim3(64, 3), blk, 0, stream>>>(x, Wq, bq, Qb, 8192, 384, 384, SC);
  gemm_nt<1, 0, 1><<<dim3(64, 3), blk, 0, stream>>>(y, Wk, bk, Kb, 8192, 384, 384, 1.0f);
  gemm_nt<0, 0, 1><<<dim3(3, 64), blk, 0, stream>>>(Wv, y, bv, Vt, 384, 8192, 384, 1.0f);
  flash_attn<<<dim3(256), dim3(512), 0, stream>>>(Qb, Kb, Vt, ctx);
  combine_norm<<<dim3(2048), dim3(256), 0, stream>>>(ctx, x, Xn);
  gemm_nt<1, 1, 0><<<dim3(64, 3), blk, 0, stream>>>(Xn, Wo, bo, (float*)d_out, 8192, 384, 384, 1.0f);
}

// Round 11
// 302.111 us; speedup vs baseline: 1.1455x; 1.1455x over previous
//
#include <hip/hip_runtime.h>
#include <stdint.h>

// ---------------------------------------------------------------------------
// Fused: Q=x@Wq^T+bq; K=y@Wk^T+bk; V=y@Wv^T+bv; ctx=softmax(QK^T/sqrt(384))@V
//        out = (x + ctx/||ctx||_row) @ Wo^T + bo        (N=M=8192, D=384)
// softmax: no max-subtraction needed (logit sigma ~0.33); denominator cancels
// under F.normalize. Scale*log2e folded into Q projection -> P = exp2(S).
// v11 = EXACT r4 resubmission (the only configuration that passed full
// replay validation; 302us). Re-banking green after four failed deviations:
//   merged-GEMM kernels => abort (r5-r7)
//   bf16 ctx            => NaN (r8)
//   2-barrier counted-vmcnt => -25% (r9)
//   dual S-chain QK     => replay divergence (r10)
// All four are permanently banned. This run doubles as an environment-
// stability control: r4 passed twice-structured validation; failure here
// would convict the container, not the code.
// ws layout: Qb bf16[8192,384]@0; Kb@6291456; Vt bf16[384,8192]@12582912;
//            Xn bf16[8192,384]@18874368; ctx f32[4][8192,384]@25165824
// ---------------------------------------------------------------------------

typedef __attribute__((ext_vector_type(8))) short bf16x8;
typedef __attribute__((ext_vector_type(4))) float f32x4;
typedef __attribute__((ext_vector_type(16))) float f32x16;

#define DEV static __device__ __forceinline__

DEV short f2bf(float f) {
  uint32_t u = __builtin_bit_cast(uint32_t, f);
  u += 0x7fffu + ((u >> 16) & 1u);   // round-to-nearest-even
  return (short)(u >> 16);
}
DEV uint32_t pack2(float a, float b) {
  return (uint32_t)(uint16_t)f2bf(a) | ((uint32_t)(uint16_t)f2bf(b) << 16);
}
DEV unsigned cvt_pk(float lo, float hi) {
  unsigned r;
  asm("v_cvt_pk_bf16_f32 %0, %1, %2" : "=v"(r) : "v"(lo), "v"(hi));
  return r;
}
DEV void pl32swap(unsigned& a, unsigned& b) {
  asm volatile("v_permlane32_swap_b32 %0, %1" : "+v"(a), "+v"(b));
}
DEV void gload16(const void* g, void* l) {
  __builtin_amdgcn_global_load_lds(
      (const __attribute__((address_space(1))) unsigned*)g,
      (__attribute__((address_space(3))) unsigned*)l, 16, 0, 0);
}

// ---------------------------------------------------------------------------
// Generic GEMM-NT: C[m,n] = (sum_k A[m,k]*B[n,k] + bias) * scale
// A: f32 or bf16 row-major [M,K]; B: f32 row-major [N,K].
// BIAS_ON_N: bias[n] else bias[m]. OUT_F32: f32 else bf16 out.
// Tile 128x128, BK=64, 4 waves in 2x2 (64x64/wave). LDS XOR-swizzled (row&7)<<4.
// ---------------------------------------------------------------------------
template <int BIAS_ON_N, int OUT_F32, int A_F32>
__global__ __launch_bounds__(256) void gemm_nt(
    const void* __restrict__ Aptr, const float* __restrict__ B,
    const float* __restrict__ bias, void* __restrict__ Cptr,
    int M, int N, int K, float scale) {
  __shared__ char As[128 * 128];
  __shared__ char Bs[128 * 128];
  const int tid = threadIdx.x;
  const int l = tid & 63, w = tid >> 6;
  const int lq = l & 15, lk = l >> 4;
  const int m0 = blockIdx.x * 128, n0 = blockIdx.y * 128;
  const int wr = (w >> 1) * 64, wc = (w & 1) * 64;
  f32x4 acc[4][4] = {};

  for (int k0 = 0; k0 < K; k0 += 64) {
    if (A_F32) {
      const float* A = (const float*)Aptr;
#pragma unroll
      for (int i = 0; i < 8; i++) {
        int c = tid + i * 256;
        int row = c >> 4, col = (c & 15) * 4;
        f32x4 v = *(const f32x4*)(A + (size_t)(m0 + row) * K + k0 + col);
        uint32_t lo = pack2(v.x, v.y), hi = pack2(v.z, v.w);
        int off = (row * 128 + col * 2) ^ ((row & 7) << 4);
        *(uint32_t*)(As + off) = lo;
        *(uint32_t*)(As + off + 4) = hi;
      }
    } else {
      const short* A = (const short*)Aptr;
#pragma unroll
      for (int i = 0; i < 4; i++) {
        int c = tid + i * 256;
        int row = c >> 3, col = (c & 7) * 8;
        uint4 v = *(const uint4*)(A + (size_t)(m0 + row) * K + k0 + col);
        int off = (row * 128 + col * 2) ^ ((row & 7) << 4);
        *(uint4*)(As + off) = v;
      }
    }
#pragma unroll
    for (int i = 0; i < 8; i++) {
      int c = tid + i * 256;
      int row = c >> 4, col = (c & 15) * 4;
      f32x4 v = *(const f32x4*)(B + (size_t)(n0 + row) * K + k0 + col);
      uint32_t lo = pack2(v.x, v.y), hi = pack2(v.z, v.w);
      int off = (row * 128 + col * 2) ^ ((row & 7) << 4);
      *(uint32_t*)(Bs + off) = lo;
      *(uint32_t*)(Bs + off + 4) = hi;
    }
    __syncthreads();
#pragma unroll
    for (int ks = 0; ks < 2; ks++) {
      bf16x8 af[4], bfr[4];
#pragma unroll
      for (int m = 0; m < 4; m++) {
        int row = wr + m * 16 + lq;
        af[m] = *(const bf16x8*)(As + ((row * 128 + ks * 64 + lk * 16) ^ ((row & 7) << 4)));
      }
#pragma unroll
      for (int n = 0; n < 4; n++) {
        int row = wc + n * 16 + lq;
        bfr[n] = *(const bf16x8*)(Bs + ((row * 128 + ks * 64 + lk * 16) ^ ((row & 7) << 4)));
      }
#pragma unroll
      for (int m = 0; m < 4; m++)
#pragma unroll
        for (int n = 0; n < 4; n++)
          acc[m][n] = __builtin_amdgcn_mfma_f32_16x16x32_bf16(af[m], bfr[n], acc[m][n], 0, 0, 0);
    }
    __syncthreads();
  }
#pragma unroll
  for (int m = 0; m < 4; m++) {
    int mg = m0 + wr + m * 16 + lk * 4;
#pragma unroll
    for (int n = 0; n < 4; n++) {
      int ng = n0 + wc + n * 16 + lq;
#pragma unroll
      for (int r = 0; r < 4; r++) {
        float v = (acc[m][n][r] + (BIAS_ON_N ? bias[ng] : bias[mg + r])) * scale;
        if (OUT_F32)
          ((float*)Cptr)[(size_t)(mg + r) * N + ng] = v;
        else
          ((short*)Cptr)[(size_t)(mg + r) * N + ng] = f2bf(v);
      }
    }
  }
}

// ---------------------------------------------------------------------------
// Flash numerator (r4-exact). Grid 256 = 64 q-tiles x 4 splits (split=bid&3:
// XCD x always serves split x&3 -> split K/V (3MB) L2-resident per XCD).
// Block 512 thr = 8 waves: wave w -> (qh=w&3, dh=w>>2), owns 32q x 192d.
// Tile = 32 kv. Wave does QK(t) only when dh==t&1 (K read once, not twice);
// P[32kv x 32q] bf16 crosses to partner via LDS dbuf (identity lane map).
// All waves do PV(t-1) each tile. One __syncthreads per tile.
// LDS = 2*24K (K dbuf) + 3*24K (V tribuf) + 16K (P) = 139264 B.
// ---------------------------------------------------------------------------
#define ITERS 64

__global__ __launch_bounds__(512)
__attribute__((amdgpu_waves_per_eu(2, 2))) void flash_attn(
    const short* __restrict__ Qb, const short* __restrict__ Kb,
    const short* __restrict__ Vt, float* __restrict__ ctx_part) {
  __shared__ char Ks[2][24576];      // [32 kv][768B] swz (row&7)<<4, dbuf
  __shared__ char Vs[3][24576];      // [384 d][64B] swz ((row>>1)&3)<<4, tribuf
  __shared__ char Ps[2][4][2048];    // per qh: [2 s][32 q][16 kv] bf16, dbuf
  const int tid = threadIdx.x, l = tid & 63, w = tid >> 6;
  const int l31 = l & 31, h = l >> 5;
  const int qh = w & 3, dh = w >> 2;
  const int sp = blockIdx.x & 3, qt = blockIdx.x >> 2;
  const int q0 = qt * 128 + qh * 32;
  const int kvbase = sp * 2048;
  const int pswz = ((l31 >> 2) & 7) << 4;
  const int poff = (l31 * 32 + h * 16) ^ pswz;  // P byte offset (write==read)

  // staging: waves 0-3 stage K (24 chunks), waves 4-7 stage V (24 chunks)
  int off6[6];
  const int cb = (w & 3) * 6144;  // LDS chunk base within tile buffer
  if (dh == 0) {
#pragma unroll
    for (int i = 0; i < 6; i++) {
      int d = cb + i * 1024 + l * 16;
      int krow = d / 768, kc = d - krow * 768;
      off6[i] = krow * 768 + (kc ^ ((krow & 7) << 4));
    }
  } else {
#pragma unroll
    for (int i = 0; i < 6; i++) {
      int d = cb + i * 1024 + l * 16;
      int vrow = d >> 6, vc = d & 63;
      off6[i] = vrow * 16384 + (vc ^ (((vrow >> 1) & 3) << 4));
    }
  }

  // Q B-frags resident: col q = q0+l31, k = s*16 + h*8 + j  (96 VGPR)
  bf16x8 qf[24];
  {
    const short* qrow = Qb + (size_t)(q0 + l31) * 384 + h * 8;
#pragma unroll
    for (int s = 0; s < 24; s++) qf[s] = *(const bf16x8*)(qrow + s * 16);
  }

  // stage tile 0
  if (dh == 0) {
    const char* kb = (const char*)Kb + (size_t)kvbase * 768;
#pragma unroll
    for (int i = 0; i < 6; i++) gload16(kb + off6[i], Ks[0] + cb + i * 1024);
  } else {
    const char* vb = (const char*)Vt + (size_t)kvbase * 2;
#pragma unroll
    for (int i = 0; i < 6; i++) gload16(vb + off6[i], Vs[0] + cb + i * 1024);
  }

  f32x16 acc[6] = {};
  __syncthreads();  // tile 0 staged

#pragma unroll 1
  for (int t = 0; t < ITERS; t++) {
    // ---- issue stage(t+1): lands anytime this tile (slots unused by readers)
    if (t < ITERS - 1) {
      int kv0 = kvbase + (t + 1) * 32;
      if (dh == 0) {
        const char* kb = (const char*)Kb + (size_t)kv0 * 768;
        char* dst = Ks[(t + 1) & 1] + cb;
#pragma unroll
        for (int i = 0; i < 6; i++) gload16(kb + off6[i], dst + i * 1024);
      } else {
        const char* vb = (const char*)Vt + (size_t)kv0 * 2;
        char* dst = Vs[(t + 1) % 3] + cb;
#pragma unroll
        for (int i = 0; i < 6; i++) gload16(vb + off6[i], dst + i * 1024);
      }
    }

    // ---- QK(t) duty: S^T = K Q^T, P -> LDS (my qh's slot) ----
    if (dh == (t & 1)) {
      f32x16 S = {};
      const char* kcb = Ks[t & 1] + l31 * 768;
      const int swzk = (l31 & 7) << 4;
      __builtin_amdgcn_s_setprio(1);
#pragma unroll
      for (int s = 0; s < 24; s++) {
        bf16x8 k0 = *(const bf16x8*)(kcb + ((s * 32 + h * 16) ^ swzk));
        S = __builtin_amdgcn_mfma_f32_32x32x16_bf16(k0, qf[s], S, 0, 0, 0);
      }
      __builtin_amdgcn_s_setprio(0);
      unsigned a0 = cvt_pk(__builtin_amdgcn_exp2f(S[0]), __builtin_amdgcn_exp2f(S[1]));
      unsigned a1 = cvt_pk(__builtin_amdgcn_exp2f(S[2]), __builtin_amdgcn_exp2f(S[3]));
      unsigned a2 = cvt_pk(__builtin_amdgcn_exp2f(S[4]), __builtin_amdgcn_exp2f(S[5]));
      unsigned a3 = cvt_pk(__builtin_amdgcn_exp2f(S[6]), __builtin_amdgcn_exp2f(S[7]));
      pl32swap(a0, a2); pl32swap(a1, a3);
      uint4 pw0 = {a0, a1, a2, a3};
      unsigned b0 = cvt_pk(__builtin_amdgcn_exp2f(S[8]), __builtin_amdgcn_exp2f(S[9]));
      unsigned b1 = cvt_pk(__builtin_amdgcn_exp2f(S[10]), __builtin_amdgcn_exp2f(S[11]));
      unsigned b2 = cvt_pk(__builtin_amdgcn_exp2f(S[12]), __builtin_amdgcn_exp2f(S[13]));
      unsigned b3 = cvt_pk(__builtin_amdgcn_exp2f(S[14]), __builtin_amdgcn_exp2f(S[15]));
      pl32swap(b0, b2); pl32swap(b1, b3);
      uint4 pw1 = {b0, b1, b2, b3};
      char* pwb = Ps[t & 1][qh];
      *(uint4*)(pwb + poff) = pw0;
      *(uint4*)(pwb + 1024 + poff) = pw1;
    }

    // ---- PV(t-1): all waves, own (qh,dh) partition ----
    if (t > 0) {
      const char* pb = Ps[(t - 1) & 1][qh];
      bf16x8 pf0 = *(const bf16x8*)(pb + poff);
      bf16x8 pf1 = *(const bf16x8*)(pb + 1024 + poff);
      const char* vb = Vs[(t - 1) % 3];
      __builtin_amdgcn_s_setprio(1);
#pragma unroll
      for (int nf = 0; nf < 6; nf++) {
        int vr = dh * 192 + nf * 32 + l31;
        int swz = ((vr >> 1) & 3) << 4;
        const char* vrow = vb + vr * 64;
        bf16x8 v0 = *(const bf16x8*)(vrow + ((h * 16) ^ swz));
        bf16x8 v1 = *(const bf16x8*)(vrow + ((32 + h * 16) ^ swz));
        acc[nf] = __builtin_amdgcn_mfma_f32_32x32x16_bf16(v0, pf0, acc[nf], 0, 0, 0);
        acc[nf] = __builtin_amdgcn_mfma_f32_32x32x16_bf16(v1, pf1, acc[nf], 0, 0, 0);
      }
      __builtin_amdgcn_s_setprio(0);
    }
    __syncthreads();  // drains DMA (vmcnt) + P writes (lgkm); one barrier/tile
  }

  // ---- tail: PV(63) ----
  {
    const char* pb = Ps[(ITERS - 1) & 1][qh];
    bf16x8 pf0 = *(const bf16x8*)(pb + poff);
    bf16x8 pf1 = *(const bf16x8*)(pb + 1024 + poff);
    const char* vb = Vs[(ITERS - 1) % 3];
#pragma unroll
    for (int nf = 0; nf < 6; nf++) {
      int vr = dh * 192 + nf * 32 + l31;
      int swz = ((vr >> 1) & 3) << 4;
      const char* vrow = vb + vr * 64;
      bf16x8 v0 = *(const bf16x8*)(vrow + ((h * 16) ^ swz));
      bf16x8 v1 = *(const bf16x8*)(vrow + ((32 + h * 16) ^ swz));
      acc[nf] = __builtin_amdgcn_mfma_f32_32x32x16_bf16(v0, pf0, acc[nf], 0, 0, 0);
      acc[nf] = __builtin_amdgcn_mfma_f32_32x32x16_bf16(v1, pf1, acc[nf], 0, 0, 0);
    }
  }

  // ---- epilogue: ctx^T frags -> ctx_part[sp][q][d]; lane owns one q row ----
  float* outp = ctx_part + (size_t)sp * 8192 * 384 + (size_t)(q0 + l31) * 384;
#pragma unroll
  for (int nf = 0; nf < 6; nf++) {
#pragma unroll
    for (int qd = 0; qd < 4; qd++) {
      f32x4 v = {acc[nf][qd * 4 + 0], acc[nf][qd * 4 + 1],
                 acc[nf][qd * 4 + 2], acc[nf][qd * 4 + 3]};
      *(f32x4*)(outp + dh * 192 + nf * 32 + qd * 8 + h * 4) = v;
    }
  }
}

// ---------------------------------------------------------------------------
// Combine: ctx = sum splits; Xn = bf16(x + ctx/||ctx||)  (softmax denominator
// cancelled analytically). One wave per q row.
// ---------------------------------------------------------------------------
__global__ __launch_bounds__(256) void combine_norm(
    const float* __restrict__ ctx_part, const float* __restrict__ x,
    short* __restrict__ Xn) {
  const int l = threadIdx.x & 63, w = threadIdx.x >> 6;
  const int q = blockIdx.x * 4 + w;
  const size_t SLAB = (size_t)8192 * 384;
  float v[6];
  float ss = 0.f;
#pragma unroll
  for (int i = 0; i < 6; i++) {
    size_t off = (size_t)q * 384 + i * 64 + l;
    float s = ctx_part[off] + ctx_part[off + SLAB] + ctx_part[off + 2 * SLAB] +
              ctx_part[off + 3 * SLAB];
    v[i] = s;
    ss += s * s;
  }
#pragma unroll
  for (int m = 1; m <= 32; m <<= 1) ss += __shfl_xor(ss, m);
  float inv = 1.0f / fmaxf(sqrtf(ss), 1e-12f);
#pragma unroll
  for (int i = 0; i < 6; i++) {
    size_t off = (size_t)q * 384 + i * 64 + l;
    Xn[off] = f2bf(x[off] + v[i] * inv);
  }
}

// ---------------------------------------------------------------------------
extern "C" void kernel_launch(void* const* d_in, const int* in_sizes, int n_in,
                              void* d_out, int out_size, void* d_ws, size_t ws_size,
                              hipStream_t stream) {
  (void)in_sizes; (void)n_in; (void)out_size; (void)ws_size;
  const float* x  = (const float*)d_in[0];
  const float* y  = (const float*)d_in[1];
  const float* Wq = (const float*)d_in[2];
  const float* bq = (const float*)d_in[3];
  const float* Wk = (const float*)d_in[4];
  const float* bk = (const float*)d_in[5];
  const float* Wv = (const float*)d_in[6];
  const float* bv = (const float*)d_in[7];
  const float* Wo = (const float*)d_in[8];
  const float* bo = (const float*)d_in[9];

  char* ws = (char*)d_ws;
  short* Qb = (short*)(ws);
  short* Kb = (short*)(ws + 6291456);
  short* Vt = (short*)(ws + 12582912);
  short* Xn = (short*)(ws + 18874368);
  float* ctx = (float*)(ws + 25165824);  // f32 [4][8192][384]

  const float SC = 0.07362233f;  // (1/sqrt(384)) * log2(e), folded into Q
  dim3 blk(256);
  gemm_nt<1, 0, 1><<<dim3(64, 3), blk, 0, stream>>>(x, Wq, bq, Qb, 8192, 384, 384, SC);
  gemm_nt<1, 0, 1><<<dim3(64, 3), blk, 0, stream>>>(y, Wk, bk, Kb, 8192, 384, 384, 1.0f);
  gemm_nt<0, 0, 1><<<dim3(3, 64), blk, 0, stream>>>(Wv, y, bv, Vt, 384, 8192, 384, 1.0f);
  flash_attn<<<dim3(256), dim3(512), 0, stream>>>(Qb, Kb, Vt, ctx);
  combine_norm<<<dim3(2048), dim3(256), 0, stream>>>(ctx, x, Xn);
  gemm_nt<1, 1, 0><<<dim3(64, 3), blk, 0, stream>>>(Xn, Wo, bo, (float*)d_out, 8192, 384, 384, 1.0f);
}